// Round 3
// baseline (694.444 us; speedup 1.0000x reference)
//
#include <hip/hip_runtime.h>

// LightGCN: N=U+I nodes, D=64 features, E edges (symmetrized to 2E directed).
// CSR built per call via bucket sort (256-row buckets). Degrees/dis come from
// the per-bucket LDS counting-sort histogram in csr_build (NO scattered global
// atomics -- R6 showed those cost 323us via 64B-line write amplification).
// Rows PADDED to multiples of 8 with sentinel zero-row N -> branch-free SpMM.
// x stored pre-scaled: xs[c] = dis[c]*x[c] (bf16x2 packed, row = 128B):
// S = sum xs[c]; x_new = dr*S; xs_next = dr^2*S.
// R8: REVERTED fdot2_f32_bf16 accumulate -- wrong results on gfx950 (absmax
// 2.2e-2). Shift-add unpack is exact.
// R9: spmm restructured ROW-PER-OCTET: 8 rows per wave, lane=(o=row slot,
// dp=uint4 slot). Kills ds_bpermute AND the 48-instr/row shuffle tail AND 8x
// of the per-row prologue/epilogue (tail+prologue were 37% of issued instrs;
// R7 profile showed latency/issue-bound: HBM 44% (mostly LLC traffic, xs
// table is LLC-resident), VALUBusy 57%). Col indices are octet-uniform: one
// uint4 col load covers 4 neighbors. Octets past their own row's end gather
// the L1-hot sentinel row N (zeros) -- branch-free imbalance padding.

static constexpr int D = 64;
#define BSHIFT 8
#define BROWS 256               // rows per bucket
#define KP 1024                 // padded bucket count for scans (>= KB=587)
#define TILE 2048               // entries per bucket_scatter block (256 thr x 8)
#define PADSLACK (7 * BROWS)    // max pad growth per bucket (rows pad to x8)
#define CSR_LDS_CAP 12288       // half-bucket staging entries (48 KB LDS)
#define COLS_SLACK 8192         // safe over-read slack for spmm uint4 col loads

__device__ __forceinline__ float bflo(unsigned v) {
    unsigned u = v << 16;
    return __builtin_bit_cast(float, u);
}
__device__ __forceinline__ float bfhi(unsigned v) {
    unsigned u = v & 0xFFFF0000u;
    return __builtin_bit_cast(float, u);
}
__device__ __forceinline__ unsigned pack_bf16x2(float a, float b) {
    unsigned ua = __builtin_bit_cast(unsigned, a);
    unsigned ub = __builtin_bit_cast(unsigned, b);
    ua += 0x7FFFu + ((ua >> 16) & 1u);   // RNE
    ub += 0x7FFFu + ((ub >> 16) & 1u);
    return (ua >> 16) | (ub & 0xFFFF0000u);
}

// bf16x2 pair accumulate: se += lo, so += hi. Exact f32 adds (R8: do NOT use
// fdot2_f32_bf16 here -- wrong results on gfx950, see header note).
__device__ __forceinline__ void acc_bf2(unsigned u, float& se, float& so) {
    se += bflo(u);
    so += bfhi(u);
}

// ---- Pass 0: per-bucket histogram (LDS only; int4-vectorized edge reads) ----
__global__ __launch_bounds__(256) void bucket_count(
        const int* __restrict__ eu, const int* __restrict__ ei,
        int* __restrict__ bcnt, int E, int U) {
    __shared__ int h[KP];
    int tid = threadIdx.x;
#pragma unroll
    for (int k = 0; k < 4; ++k) h[tid + k * 256] = 0;
    __syncthreads();
    int E4 = E >> 2;
    int stride = gridDim.x * blockDim.x;
    int g = blockIdx.x * blockDim.x + tid;
    const int4* eu4 = (const int4*)eu;
    const int4* ei4 = (const int4*)ei;
    for (int e = g; e < E4; e += stride) {
        int4 u = eu4[e];
        int4 it = ei4[e];
        atomicAdd(&h[u.x >> BSHIFT], 1);
        atomicAdd(&h[u.y >> BSHIFT], 1);
        atomicAdd(&h[u.z >> BSHIFT], 1);
        atomicAdd(&h[u.w >> BSHIFT], 1);
        atomicAdd(&h[(U + it.x) >> BSHIFT], 1);
        atomicAdd(&h[(U + it.y) >> BSHIFT], 1);
        atomicAdd(&h[(U + it.z) >> BSHIFT], 1);
        atomicAdd(&h[(U + it.w) >> BSHIFT], 1);
    }
    if (blockIdx.x == 0 && tid < (E - (E4 << 2))) {   // tail (<4 edges)
        int e = (E4 << 2) + tid;
        atomicAdd(&h[eu[e] >> BSHIFT], 1);
        atomicAdd(&h[(U + ei[e]) >> BSHIFT], 1);
    }
    __syncthreads();
#pragma unroll
    for (int k = 0; k < 4; ++k) {
        int v = h[tid + k * 256];
        if (v) atomicAdd(&bcnt[tid + k * 256], v);
    }
}

// ---- Pass 1: scan bucket counts -> bucket bases + global cursors ----
__global__ void bscan(const int* __restrict__ bcnt, int* __restrict__ bbase,
                      int* __restrict__ bcursor, int KB, int twoE) {
    __shared__ int s[KP];
    int tid = threadIdx.x; // 1024 threads, 1 block
    int v = (tid < KB) ? bcnt[tid] : 0;
    s[tid] = v;
    __syncthreads();
    for (int off = 1; off < KP; off <<= 1) {
        int a = (tid >= off) ? s[tid - off] : 0;
        __syncthreads();
        s[tid] += a;
        __syncthreads();
    }
    int ex = s[tid] - v; // exclusive
    if (tid < KB) { bbase[tid] = ex; bcursor[tid] = ex; }
    if (tid == KB) bbase[tid] = twoE;
    if (tid > KB) bcursor[tid] = 0;
}

// ---- Pass 2: scatter entries into bucket-grouped pairs buffer ----
// packed entry: (row & 255) << 18 | col   (col < 2^18)
__global__ __launch_bounds__(256) void bucket_scatter(
        const int* __restrict__ eu, const int* __restrict__ ei,
        int* __restrict__ bcursor, unsigned* __restrict__ pairs,
        int E, int U, int twoE) {
    __shared__ int hist[KP];           // counts -> local running cursor
    __shared__ int sbase[KP];          // tile-local exclusive base
    __shared__ int gbase[KP];          // reserved global base
    __shared__ unsigned staging[TILE];
    __shared__ unsigned short sb[TILE];
    int tid = threadIdx.x;
#pragma unroll
    for (int k = 0; k < 4; ++k) hist[tid + k * 256] = 0;
    __syncthreads();
    int base_e = blockIdx.x * TILE;
    int bk[8]; unsigned pk[8];
#pragma unroll
    for (int k = 0; k < 8; ++k) {
        int e = base_e + k * 256 + tid;
        bk[k] = -1;
        if (e < twoE) {
            int r, c;
            if (e < E) { r = eu[e]; c = U + ei[e]; }
            else       { c = eu[e - E]; r = U + ei[e - E]; }
            int b = r >> BSHIFT;
            bk[k] = b;
            pk[k] = ((unsigned)(r & (BROWS - 1)) << 18) | (unsigned)c;
            atomicAdd(&hist[b], 1);
        }
    }
    __syncthreads();
    int cc[4];
#pragma unroll
    for (int k = 0; k < 4; ++k) cc[k] = hist[tid + k * 256];
    for (int off = 1; off < KP; off <<= 1) {
        int a[4];
#pragma unroll
        for (int k = 0; k < 4; ++k) {
            int idx = tid + k * 256;
            a[k] = (idx >= off) ? hist[idx - off] : 0;
        }
        __syncthreads();
#pragma unroll
        for (int k = 0; k < 4; ++k) hist[tid + k * 256] += a[k];
        __syncthreads();
    }
#pragma unroll
    for (int k = 0; k < 4; ++k) {
        int idx = tid + k * 256;
        int e0 = hist[idx] - cc[k];
        sbase[idx] = e0;
        if (cc[k] > 0) gbase[idx] = atomicAdd(&bcursor[idx], cc[k]);
        hist[idx] = e0;     // own-slot overwrite, no cross reads
    }
    __syncthreads();
#pragma unroll
    for (int k = 0; k < 8; ++k) {
        if (bk[k] >= 0) {
            int pos = atomicAdd(&hist[bk[k]], 1);
            staging[pos] = pk[k];
            sb[pos] = (unsigned short)bk[k];
        }
    }
    __syncthreads();
    int tile_n = min(TILE, twoE - base_e);
#pragma unroll
    for (int k = 0; k < 8; ++k) {
        int j = k * 256 + tid;
        if (j < tile_n) {
            int b = sb[j];
            pairs[gbase[b] + (j - sbase[b])] = staging[j];
        }
    }
}

// ---- Pass 3: per-bucket counting sort -> deg/row_ptr/dis/cols ----
// 256 threads, one thread per row. Padded base = bbase[b] + 1792*b.
// Cols staged in LDS per HALF-bucket (keeps 3 blocks/CU), flushed coalesced.
__global__ __launch_bounds__(256) void csr_build(
        const unsigned* __restrict__ pairs, const int* __restrict__ bbase,
        int* __restrict__ deg, int* __restrict__ row_ptr, float* __restrict__ dis,
        int* __restrict__ cols, int N) {
    __shared__ int cnt[BROWS];
    __shared__ int cur[BROWS];
    __shared__ int fin[BROWS];
    __shared__ int lbuf[CSR_LDS_CAP];
    __shared__ int meta[2];            // [0]=padded offset of row 128, [1]=total
    int tid = threadIdx.x;
    int b = blockIdx.x;
    int lo = bbase[b], hi = bbase[b + 1];
    int cbase = lo + PADSLACK * b;
    cnt[tid] = 0;
    __syncthreads();
    for (int i = lo + tid; i < hi; i += 256) atomicAdd(&cnt[pairs[i] >> 18], 1);
    __syncthreads();
    int c = cnt[tid];
    int p = (c + 7) & ~7;
    cnt[tid] = p;
    __syncthreads();
    for (int off = 1; off < BROWS; off <<= 1) {
        int a = (tid >= off) ? cnt[tid - off] : 0;
        __syncthreads();
        cnt[tid] += a;
        __syncthreads();
    }
    int e = cnt[tid] - p; // exclusive padded offset within bucket
    int r = (b << BSHIFT) + tid;
    if (r < N) {
        deg[r] = c;
        row_ptr[r] = cbase + e;
        dis[r] = rsqrtf((float)c + 1e-7f);
    }
    cur[tid] = e;
    fin[tid] = e + p;
    if (tid == 127) meta[0] = cnt[127];
    if (tid == 255) meta[1] = cnt[255];
    __syncthreads();
    int half0 = meta[0];
    int total = meta[1];
    if (half0 <= CSR_LDS_CAP && (total - half0) <= CSR_LDS_CAP) {
#pragma unroll
        for (int half = 0; half < 2; ++half) {
            int base = half ? half0 : 0;
            int end  = half ? total : half0;
            for (int i = lo + tid; i < hi; i += 256) {
                unsigned pe = pairs[i];
                int row = (int)(pe >> 18);
                if ((row >> 7) == half) {
                    int pos = atomicAdd(&cur[row], 1);
                    lbuf[pos - base] = (int)(pe & 0x3FFFFu);
                }
            }
            __syncthreads();
            if ((tid >> 7) == half) {     // sentinel pad fill for this half
                for (int i = cur[tid]; i < fin[tid]; ++i) lbuf[i - base] = N;
            }
            __syncthreads();
            for (int i = base + tid; i < end; i += 256)   // coalesced flush
                cols[cbase + i] = lbuf[i - base];
            __syncthreads();
        }
    } else {
        // fallback: direct global scatter (pathological bucket size)
        for (int i = lo + tid; i < hi; i += 256) {
            unsigned pe = pairs[i];
            int pos = atomicAdd(&cur[pe >> 18], 1);
            cols[cbase + pos] = (int)(pe & 0x3FFFFu);
        }
        __syncthreads();
        for (int i = cur[tid]; i < fin[tid]; ++i) cols[cbase + i] = N;
    }
}

// t handles 8 dims (2 float4 reads, 1 uint4 xs write, 2 float4 acc writes).
// Sentinel row N zeroed in BOTH xs buffers.
__global__ __launch_bounds__(256) void init_kernel(
        const float4* __restrict__ ue4, const float4* __restrict__ ie4,
        const float* __restrict__ dis,
        uint4* __restrict__ xsA4, uint4* __restrict__ xsB4,
        float4* __restrict__ acc4, int U8, int N8) {
    int t = blockIdx.x * blockDim.x + threadIdx.x;
    if (t >= N8 + 8) return;
    if (t >= N8) {                        // sentinel zero-row N (both buffers)
        uint4 z = {0u, 0u, 0u, 0u};
        xsA4[t] = z;
        xsB4[t] = z;
        return;
    }
    float dv = dis[t >> 3];
    const float4* src = (t < U8) ? (ue4 + 2 * t) : (ie4 + 2 * (t - U8));
    float4 a0 = src[0];
    float4 a1 = src[1];
    acc4[2 * t] = a0;
    acc4[2 * t + 1] = a1;
    uint4 w;
    w.x = pack_bf16x2(dv * a0.x, dv * a0.y);
    w.y = pack_bf16x2(dv * a0.z, dv * a0.w);
    w.z = pack_bf16x2(dv * a1.x, dv * a1.y);
    w.w = pack_bf16x2(dv * a1.z, dv * a1.w);
    xsA4[t] = w;
}

// R9 spmm: 8 rows per wave. lane = (o = lane>>3: row slot, dp = lane&7: uint4
// slot within the 128B row). Per k4 step each octet processes 4 neighbors of
// ITS row: one octet-uniform uint4 col load + 4 gathers (each gather instr
// still covers 8 random 128B rows across the wave). Octets whose row is done
// (k4 >= own cntp) gather the sentinel zero-row N (L1-hot). No bpermute, no
// cross-lane reduction, no per-row tail: lane's s0..s7 are final dims
// dp*8..dp*8+7 of its octet's row; epilogue is fully parallel across lanes.
__global__ __launch_bounds__(256) void spmm_kernel(
        const int* __restrict__ row_ptr, const int* __restrict__ deg,
        const float* __restrict__ dis, const int* __restrict__ cols,
        const unsigned* __restrict__ xs, unsigned* __restrict__ xs_next,
        float4* __restrict__ acc4, int N, float final_scale) {
    int wid = blockIdx.x * 4 + (threadIdx.x >> 6);
    int lane = threadIdx.x & 63;
    int o = lane >> 3;
    int dp = lane & 7;
    int r = wid * 8 + o;
    int rc = min(r, N - 1);
    int start = row_ptr[rc];
    int dg = deg[rc];
    float dr = dis[rc];
    int cntp = (r < N) ? ((dg + 7) & ~7) : 0;
    int mx = cntp;
    mx = max(mx, __shfl_xor(mx, 8));
    mx = max(mx, __shfl_xor(mx, 16));
    mx = max(mx, __shfl_xor(mx, 32));
    const int* colp = cols + start;
    unsigned dpo = (unsigned)(dp << 2);      // dword offset within row
    float s0 = 0.f, s1 = 0.f, s2 = 0.f, s3 = 0.f;
    float s4 = 0.f, s5 = 0.f, s6 = 0.f, s7 = 0.f;
    for (int k4 = 0; k4 < mx; k4 += 4) {
        bool act = (k4 < cntp);              // octet-uniform
        int kk = act ? k4 : 0;               // keep load in-bounds of own row
        uint4 cq = *(const uint4*)(colp + kk);
        unsigned c0 = act ? cq.x : (unsigned)N;
        unsigned c1 = act ? cq.y : (unsigned)N;
        unsigned c2 = act ? cq.z : (unsigned)N;
        unsigned c3 = act ? cq.w : (unsigned)N;
        uint4 v0 = *(const uint4*)(xs + (c0 << 5) + dpo);
        uint4 v1 = *(const uint4*)(xs + (c1 << 5) + dpo);
        uint4 v2 = *(const uint4*)(xs + (c2 << 5) + dpo);
        uint4 v3 = *(const uint4*)(xs + (c3 << 5) + dpo);
        acc_bf2(v0.x, s0, s1); acc_bf2(v0.y, s2, s3);
        acc_bf2(v0.z, s4, s5); acc_bf2(v0.w, s6, s7);
        acc_bf2(v1.x, s0, s1); acc_bf2(v1.y, s2, s3);
        acc_bf2(v1.z, s4, s5); acc_bf2(v1.w, s6, s7);
        acc_bf2(v2.x, s0, s1); acc_bf2(v2.y, s2, s3);
        acc_bf2(v2.z, s4, s5); acc_bf2(v2.w, s6, s7);
        acc_bf2(v3.x, s0, s1); acc_bf2(v3.y, s2, s3);
        acc_bf2(v3.z, s4, s5); acc_bf2(v3.w, s6, s7);
    }
    if (r < N) {
        float x0 = dr * s0, x1 = dr * s1, x2 = dr * s2, x3 = dr * s3;
        float x4 = dr * s4, x5 = dr * s5, x6 = dr * s6, x7 = dr * s7;
        uint4 w;
        w.x = pack_bf16x2(dr * x0, dr * x1);   // xs_next = dr^2 * S
        w.y = pack_bf16x2(dr * x2, dr * x3);
        w.z = pack_bf16x2(dr * x4, dr * x5);
        w.w = pack_bf16x2(dr * x6, dr * x7);
        ((uint4*)xs_next)[(r << 3) + dp] = w;
        int oo = (r << 4) + (dp << 1);
        float4 a = acc4[oo];
        a.x = (a.x + x0) * final_scale;
        a.y = (a.y + x1) * final_scale;
        a.z = (a.z + x2) * final_scale;
        a.w = (a.w + x3) * final_scale;
        acc4[oo] = a;
        float4 b2 = acc4[oo + 1];
        b2.x = (b2.x + x4) * final_scale;
        b2.y = (b2.y + x5) * final_scale;
        b2.z = (b2.z + x6) * final_scale;
        b2.w = (b2.w + x7) * final_scale;
        acc4[oo + 1] = b2;
    }
}

extern "C" void kernel_launch(void* const* d_in, const int* in_sizes, int n_in,
                              void* d_out, int out_size, void* d_ws, size_t ws_size,
                              hipStream_t stream) {
    const float* ue = (const float*)d_in[0];
    const float* ie = (const float*)d_in[1];
    const int* eu = (const int*)d_in[2];
    const int* ei = (const int*)d_in[3];
    const int U = in_sizes[0] / D; // 100001
    const int I = in_sizes[1] / D; // 50001
    const int N = U + I;           // 150002
    const int E = in_sizes[2];     // 4,000,000
    const int twoE = 2 * E;
    const int KB = (N + BROWS - 1) / BROWS; // 587
    float* out = (float*)d_out;

    char* ws = (char*)d_ws;
    auto alloc = [&](size_t bytes) {
        char* p = ws;
        ws += (bytes + 255) & ~(size_t)255;
        return p;
    };
    int* deg = (int*)alloc((size_t)N * 4);
    int* row_ptr = (int*)alloc((size_t)N * 4);
    float* dis = (float*)alloc((size_t)N * 4);
    int* bcnt = (int*)alloc(KP * 4);
    int* bbase = (int*)alloc((KP + 1) * 4);
    int* bcursor = (int*)alloc(KP * 4);
    int* cols = (int*)alloc(((size_t)twoE + (size_t)PADSLACK * (KB + 1) + COLS_SLACK) * 4);
    unsigned* pairs = (unsigned*)alloc((size_t)twoE * 4);
    unsigned* xsA = (unsigned*)alloc(((size_t)N + 1) * 32 * 4); // bf16x2, +sentinel row
    unsigned* xsB = (unsigned*)alloc(((size_t)N + 1) * 32 * 4);

    hipMemsetAsync(bcnt, 0, KP * 4, stream);
    bucket_count<<<1024, 256, 0, stream>>>(eu, ei, bcnt, E, U);
    bscan<<<1, KP, 0, stream>>>(bcnt, bbase, bcursor, KB, twoE);
    bucket_scatter<<<(twoE + TILE - 1) / TILE, 256, 0, stream>>>(
        eu, ei, bcursor, pairs, E, U, twoE);
    csr_build<<<KB, BROWS, 0, stream>>>(pairs, bbase, deg, row_ptr, dis, cols, N);

    int N8 = N * 8, U8 = U * 8;
    init_kernel<<<(N8 + 8 + 255) / 256, 256, 0, stream>>>(
        (const float4*)ue, (const float4*)ie, dis,
        (uint4*)xsA, (uint4*)xsB, (float4*)out, U8, N8);

    unsigned* x = xsA;
    unsigned* xn = xsB;
    int nwaves = (N + 7) / 8;
    int nblocks = (nwaves + 3) / 4;
    for (int l = 0; l < 3; ++l) {
        float fs = (l == 2) ? 0.25f : 1.0f;
        spmm_kernel<<<nblocks, 256, 0, stream>>>(
            row_ptr, deg, dis, cols, x, xn, (float4*)out, N, fs);
        unsigned* tmp = x; x = xn; xn = tmp;
    }
}

// Round 4
// 620.099 us; speedup vs baseline: 1.1199x; 1.1199x over previous
//
#include <hip/hip_runtime.h>

// LightGCN: N=U+I nodes, D=64 features, E edges (symmetrized to 2E directed).
// CSR built per call via bucket sort (256-row buckets). Degrees/dis come from
// the per-bucket LDS counting-sort histogram in csr_build (NO scattered global
// atomics -- R6 showed those cost 323us via 64B-line write amplification).
// Rows PADDED to multiples of 8 with sentinel zero-row N -> branch-free SpMM.
// x stored pre-scaled: xs[c] = dis[c]*x[c] (bf16x2 packed, row = 128B):
// S = sum xs[c]; x_new = dr*S; xs_next = dr^2*S.
// R8: NO fdot2_f32_bf16 (wrong results on gfx950, absmax 2.2e-2).
// R9 (REVERTED): row-per-octet spmm regressed 117->131us: compiler dropped
// in-flight gathers to ~1 (VGPR 20) and per-octet 16B col loads amplified
// cols traffic (FETCH 346->413MB). Back to R7 phase-split, wave-per-row.
// R10 theory: spmm is BYTES-bound at a ~3.5 TB/s plateau for this random
// 64-128B traffic (3 different structures all land 3.3-3.7 TB/s; dur tracks
// bytes linearly). So: cut bytes. Eliminate f32 acc RMW (38R+38W MB/layer):
// layers 0/1 write xs_next + a compact f16 x_l copy (19MB, relerr 2^-12);
// layer 2 reads emb + xh1 + xh2 and writes out once. init no longer writes
// acc. xs2 ping-pongs into xsA (A dead after layer 0); xh1 aliases the dead
// `pairs` buffer. Net -133MB => predicted ~595-610us total.

static constexpr int D = 64;
#define BSHIFT 8
#define BROWS 256               // rows per bucket
#define KP 1024                 // padded bucket count for scans (>= KB=587)
#define TILE 2048               // entries per bucket_scatter block (256 thr x 8)
#define PADSLACK (7 * BROWS)    // max pad growth per bucket (rows pad to x8)
#define CSR_LDS_CAP 12288       // half-bucket staging entries (48 KB LDS)
#define COLS_SLACK 8192         // safe over-read slack for spmm col loads

__device__ __forceinline__ float bflo(unsigned v) {
    unsigned u = v << 16;
    return __builtin_bit_cast(float, u);
}
__device__ __forceinline__ float bfhi(unsigned v) {
    unsigned u = v & 0xFFFF0000u;
    return __builtin_bit_cast(float, u);
}
__device__ __forceinline__ unsigned pack_bf16x2(float a, float b) {
    unsigned ua = __builtin_bit_cast(unsigned, a);
    unsigned ub = __builtin_bit_cast(unsigned, b);
    ua += 0x7FFFu + ((ua >> 16) & 1u);   // RNE
    ub += 0x7FFFu + ((ub >> 16) & 1u);
    return (ua >> 16) | (ub & 0xFFFF0000u);
}
// f16 pack/unpack for the x_l recovery arrays (RNE via _Float16 cast).
__device__ __forceinline__ unsigned pack_f16x2(float a, float b) {
    unsigned short ua = __builtin_bit_cast(unsigned short, (_Float16)a);
    unsigned short ub = __builtin_bit_cast(unsigned short, (_Float16)b);
    return (unsigned)ua | ((unsigned)ub << 16);
}
__device__ __forceinline__ float f16lo(unsigned v) {
    return (float)__builtin_bit_cast(_Float16, (unsigned short)(v & 0xFFFFu));
}
__device__ __forceinline__ float f16hi(unsigned v) {
    return (float)__builtin_bit_cast(_Float16, (unsigned short)(v >> 16));
}

// bf16x2 pair accumulate: se += lo, so += hi. Exact f32 adds.
__device__ __forceinline__ void acc_bf2(unsigned u, float& se, float& so) {
    se += bflo(u);
    so += bfhi(u);
}

// ---- Pass 0: per-bucket histogram (LDS only; int4-vectorized edge reads) ----
__global__ __launch_bounds__(256) void bucket_count(
        const int* __restrict__ eu, const int* __restrict__ ei,
        int* __restrict__ bcnt, int E, int U) {
    __shared__ int h[KP];
    int tid = threadIdx.x;
#pragma unroll
    for (int k = 0; k < 4; ++k) h[tid + k * 256] = 0;
    __syncthreads();
    int E4 = E >> 2;
    int stride = gridDim.x * blockDim.x;
    int g = blockIdx.x * blockDim.x + tid;
    const int4* eu4 = (const int4*)eu;
    const int4* ei4 = (const int4*)ei;
    for (int e = g; e < E4; e += stride) {
        int4 u = eu4[e];
        int4 it = ei4[e];
        atomicAdd(&h[u.x >> BSHIFT], 1);
        atomicAdd(&h[u.y >> BSHIFT], 1);
        atomicAdd(&h[u.z >> BSHIFT], 1);
        atomicAdd(&h[u.w >> BSHIFT], 1);
        atomicAdd(&h[(U + it.x) >> BSHIFT], 1);
        atomicAdd(&h[(U + it.y) >> BSHIFT], 1);
        atomicAdd(&h[(U + it.z) >> BSHIFT], 1);
        atomicAdd(&h[(U + it.w) >> BSHIFT], 1);
    }
    if (blockIdx.x == 0 && tid < (E - (E4 << 2))) {   // tail (<4 edges)
        int e = (E4 << 2) + tid;
        atomicAdd(&h[eu[e] >> BSHIFT], 1);
        atomicAdd(&h[(U + ei[e]) >> BSHIFT], 1);
    }
    __syncthreads();
#pragma unroll
    for (int k = 0; k < 4; ++k) {
        int v = h[tid + k * 256];
        if (v) atomicAdd(&bcnt[tid + k * 256], v);
    }
}

// ---- Pass 1: scan bucket counts -> bucket bases + global cursors ----
__global__ void bscan(const int* __restrict__ bcnt, int* __restrict__ bbase,
                      int* __restrict__ bcursor, int KB, int twoE) {
    __shared__ int s[KP];
    int tid = threadIdx.x; // 1024 threads, 1 block
    int v = (tid < KB) ? bcnt[tid] : 0;
    s[tid] = v;
    __syncthreads();
    for (int off = 1; off < KP; off <<= 1) {
        int a = (tid >= off) ? s[tid - off] : 0;
        __syncthreads();
        s[tid] += a;
        __syncthreads();
    }
    int ex = s[tid] - v; // exclusive
    if (tid < KB) { bbase[tid] = ex; bcursor[tid] = ex; }
    if (tid == KB) bbase[tid] = twoE;
    if (tid > KB) bcursor[tid] = 0;
}

// ---- Pass 2: scatter entries into bucket-grouped pairs buffer ----
// packed entry: (row & 255) << 18 | col   (col < 2^18)
__global__ __launch_bounds__(256) void bucket_scatter(
        const int* __restrict__ eu, const int* __restrict__ ei,
        int* __restrict__ bcursor, unsigned* __restrict__ pairs,
        int E, int U, int twoE) {
    __shared__ int hist[KP];           // counts -> local running cursor
    __shared__ int sbase[KP];          // tile-local exclusive base
    __shared__ int gbase[KP];          // reserved global base
    __shared__ unsigned staging[TILE];
    __shared__ unsigned short sb[TILE];
    int tid = threadIdx.x;
#pragma unroll
    for (int k = 0; k < 4; ++k) hist[tid + k * 256] = 0;
    __syncthreads();
    int base_e = blockIdx.x * TILE;
    int bk[8]; unsigned pk[8];
#pragma unroll
    for (int k = 0; k < 8; ++k) {
        int e = base_e + k * 256 + tid;
        bk[k] = -1;
        if (e < twoE) {
            int r, c;
            if (e < E) { r = eu[e]; c = U + ei[e]; }
            else       { c = eu[e - E]; r = U + ei[e - E]; }
            int b = r >> BSHIFT;
            bk[k] = b;
            pk[k] = ((unsigned)(r & (BROWS - 1)) << 18) | (unsigned)c;
            atomicAdd(&hist[b], 1);
        }
    }
    __syncthreads();
    int cc[4];
#pragma unroll
    for (int k = 0; k < 4; ++k) cc[k] = hist[tid + k * 256];
    for (int off = 1; off < KP; off <<= 1) {
        int a[4];
#pragma unroll
        for (int k = 0; k < 4; ++k) {
            int idx = tid + k * 256;
            a[k] = (idx >= off) ? hist[idx - off] : 0;
        }
        __syncthreads();
#pragma unroll
        for (int k = 0; k < 4; ++k) hist[tid + k * 256] += a[k];
        __syncthreads();
    }
#pragma unroll
    for (int k = 0; k < 4; ++k) {
        int idx = tid + k * 256;
        int e0 = hist[idx] - cc[k];
        sbase[idx] = e0;
        if (cc[k] > 0) gbase[idx] = atomicAdd(&bcursor[idx], cc[k]);
        hist[idx] = e0;     // own-slot overwrite, no cross reads
    }
    __syncthreads();
#pragma unroll
    for (int k = 0; k < 8; ++k) {
        if (bk[k] >= 0) {
            int pos = atomicAdd(&hist[bk[k]], 1);
            staging[pos] = pk[k];
            sb[pos] = (unsigned short)bk[k];
        }
    }
    __syncthreads();
    int tile_n = min(TILE, twoE - base_e);
#pragma unroll
    for (int k = 0; k < 8; ++k) {
        int j = k * 256 + tid;
        if (j < tile_n) {
            int b = sb[j];
            pairs[gbase[b] + (j - sbase[b])] = staging[j];
        }
    }
}

// ---- Pass 3: per-bucket counting sort -> deg/row_ptr/dis/cols ----
// 256 threads, one thread per row. Padded base = bbase[b] + 1792*b.
// Cols staged in LDS per HALF-bucket (keeps 3 blocks/CU), flushed coalesced.
__global__ __launch_bounds__(256) void csr_build(
        const unsigned* __restrict__ pairs, const int* __restrict__ bbase,
        int* __restrict__ deg, int* __restrict__ row_ptr, float* __restrict__ dis,
        int* __restrict__ cols, int N) {
    __shared__ int cnt[BROWS];
    __shared__ int cur[BROWS];
    __shared__ int fin[BROWS];
    __shared__ int lbuf[CSR_LDS_CAP];
    __shared__ int meta[2];            // [0]=padded offset of row 128, [1]=total
    int tid = threadIdx.x;
    int b = blockIdx.x;
    int lo = bbase[b], hi = bbase[b + 1];
    int cbase = lo + PADSLACK * b;
    cnt[tid] = 0;
    __syncthreads();
    for (int i = lo + tid; i < hi; i += 256) atomicAdd(&cnt[pairs[i] >> 18], 1);
    __syncthreads();
    int c = cnt[tid];
    int p = (c + 7) & ~7;
    cnt[tid] = p;
    __syncthreads();
    for (int off = 1; off < BROWS; off <<= 1) {
        int a = (tid >= off) ? cnt[tid - off] : 0;
        __syncthreads();
        cnt[tid] += a;
        __syncthreads();
    }
    int e = cnt[tid] - p; // exclusive padded offset within bucket
    int r = (b << BSHIFT) + tid;
    if (r < N) {
        deg[r] = c;
        row_ptr[r] = cbase + e;
        dis[r] = rsqrtf((float)c + 1e-7f);
    }
    cur[tid] = e;
    fin[tid] = e + p;
    if (tid == 127) meta[0] = cnt[127];
    if (tid == 255) meta[1] = cnt[255];
    __syncthreads();
    int half0 = meta[0];
    int total = meta[1];
    if (half0 <= CSR_LDS_CAP && (total - half0) <= CSR_LDS_CAP) {
#pragma unroll
        for (int half = 0; half < 2; ++half) {
            int base = half ? half0 : 0;
            int end  = half ? total : half0;
            for (int i = lo + tid; i < hi; i += 256) {
                unsigned pe = pairs[i];
                int row = (int)(pe >> 18);
                if ((row >> 7) == half) {
                    int pos = atomicAdd(&cur[row], 1);
                    lbuf[pos - base] = (int)(pe & 0x3FFFFu);
                }
            }
            __syncthreads();
            if ((tid >> 7) == half) {     // sentinel pad fill for this half
                for (int i = cur[tid]; i < fin[tid]; ++i) lbuf[i - base] = N;
            }
            __syncthreads();
            for (int i = base + tid; i < end; i += 256)   // coalesced flush
                cols[cbase + i] = lbuf[i - base];
            __syncthreads();
        }
    } else {
        // fallback: direct global scatter (pathological bucket size)
        for (int i = lo + tid; i < hi; i += 256) {
            unsigned pe = pairs[i];
            int pos = atomicAdd(&cur[pe >> 18], 1);
            cols[cbase + pos] = (int)(pe & 0x3FFFFu);
        }
        __syncthreads();
        for (int i = cur[tid]; i < fin[tid]; ++i) cols[cbase + i] = N;
    }
}

// R10 init: writes xs0 (bf16 pre-scaled) + sentinel zero-rows of BOTH xs
// buffers. NO acc write (out is produced once, by spmm_last).
__global__ __launch_bounds__(256) void init_kernel(
        const float4* __restrict__ ue4, const float4* __restrict__ ie4,
        const float* __restrict__ dis,
        uint4* __restrict__ xsA4, uint4* __restrict__ xsB4,
        int U8, int N8) {
    int t = blockIdx.x * blockDim.x + threadIdx.x;
    if (t >= N8 + 8) return;
    if (t >= N8) {                        // sentinel zero-row N (both buffers)
        uint4 z = {0u, 0u, 0u, 0u};
        xsA4[t] = z;
        xsB4[t] = z;
        return;
    }
    float dv = dis[t >> 3];
    const float4* src = (t < U8) ? (ue4 + 2 * t) : (ie4 + 2 * (t - U8));
    float4 a0 = src[0];
    float4 a1 = src[1];
    uint4 w;
    w.x = pack_bf16x2(dv * a0.x, dv * a0.y);
    w.y = pack_bf16x2(dv * a0.z, dv * a0.w);
    w.z = pack_bf16x2(dv * a1.x, dv * a1.y);
    w.w = pack_bf16x2(dv * a1.z, dv * a1.w);
    xsA4[t] = w;
}

// One wave per row. lane = (n8 = lane>>3 neighbor slot, dp = lane&7 uint4 idx).
// One uint4 load covers 8 neighbor rows per instruction; one ds_bpermute per
// octet broadcasts the 8 cols. Rows padded to x8 with sentinel -> no tail code.
// Phase-split body: all bpermutes, then all gathers (up to 8 in flight), then
// accumulate. (R7 structure -- known 117us; R9 variant regressed, reverted.)
// Layers 0/1: writes xs_next (bf16 gather table) + xh (f16 copy of x_l for
// the final sum) -- no f32 acc RMW.
__global__ __launch_bounds__(256) void spmm_mid(
        const int* __restrict__ row_ptr, const int* __restrict__ deg,
        const float* __restrict__ dis, const int* __restrict__ cols,
        const unsigned* __restrict__ xs, unsigned* __restrict__ xs_next,
        unsigned* __restrict__ xh, int N) {
    int wid = blockIdx.x * 4 + (threadIdx.x >> 6);
    if (wid >= N) return;
    int lane = threadIdx.x & 63;
    int n8 = lane >> 3;
    int dp = lane & 7;
    int start = row_ptr[wid];
    int cntp = (deg[wid] + 7) & ~7;
    float dr = dis[wid];
    const int* colp = cols + start;
    int vbase = n8 << 2;       // bpermute byte addr component
    int dpo = dp << 2;         // dword offset within row (uint4 = 4 dwords)
    float s0 = 0.f, s1 = 0.f, s2 = 0.f, s3 = 0.f;
    float s4 = 0.f, s5 = 0.f, s6 = 0.f, s7 = 0.f;
    for (int chunk = 0; chunk < cntp; chunk += 64) {
        int cv = colp[chunk + lane];           // over-read OK (slack at end)
        int nq = min(64, cntp - chunk) >> 3;
        nq = __builtin_amdgcn_readfirstlane(nq);   // wave-uniform -> SGPR branch
        int coq[8];
        uint4 vq[8];
#pragma unroll
        for (int q = 0; q < 8; ++q) {
            if (q < nq)
                coq[q] = __builtin_amdgcn_ds_bpermute((q << 5) + vbase, cv);
        }
#pragma unroll
        for (int q = 0; q < 8; ++q) {
            if (q < nq)
                vq[q] = *(const uint4*)(xs + (((unsigned)coq[q]) << 5) + dpo);
        }
#pragma unroll
        for (int q = 0; q < 8; ++q) {
            if (q < nq) {
                acc_bf2(vq[q].x, s0, s1);
                acc_bf2(vq[q].y, s2, s3);
                acc_bf2(vq[q].z, s4, s5);
                acc_bf2(vq[q].w, s6, s7);
            }
        }
    }
#pragma unroll
    for (int m = 8; m < 64; m <<= 1) {
        s0 += __shfl_xor(s0, m); s1 += __shfl_xor(s1, m);
        s2 += __shfl_xor(s2, m); s3 += __shfl_xor(s3, m);
        s4 += __shfl_xor(s4, m); s5 += __shfl_xor(s5, m);
        s6 += __shfl_xor(s6, m); s7 += __shfl_xor(s7, m);
    }
    if (n8 == 0) {
        float x0 = dr * s0, x1 = dr * s1, x2 = dr * s2, x3 = dr * s3;
        float x4 = dr * s4, x5 = dr * s5, x6 = dr * s6, x7 = dr * s7;
        uint4 w;
        w.x = pack_bf16x2(dr * x0, dr * x1);   // xs_next = dr^2 * S
        w.y = pack_bf16x2(dr * x2, dr * x3);
        w.z = pack_bf16x2(dr * x4, dr * x5);
        w.w = pack_bf16x2(dr * x6, dr * x7);
        ((uint4*)xs_next)[(wid << 3) + dp] = w;
        uint4 h;
        h.x = pack_f16x2(x0, x1);              // xh = x_l (f16, for final sum)
        h.y = pack_f16x2(x2, x3);
        h.z = pack_f16x2(x4, x5);
        h.w = pack_f16x2(x6, x7);
        ((uint4*)xh)[(wid << 3) + dp] = h;
    }
}

// Layer 2: gathers from xs2, then out = 0.25*(emb + x1 + x2 + x3).
// x1/x2 come from the f16 recovery arrays; emb re-read from inputs (f32).
__global__ __launch_bounds__(256) void spmm_last(
        const int* __restrict__ row_ptr, const int* __restrict__ deg,
        const float* __restrict__ dis, const int* __restrict__ cols,
        const unsigned* __restrict__ xs,
        const float4* __restrict__ ue4, const float4* __restrict__ ie4,
        const unsigned* __restrict__ xh1, const unsigned* __restrict__ xh2,
        float4* __restrict__ out4, int U, int N) {
    int wid = blockIdx.x * 4 + (threadIdx.x >> 6);
    if (wid >= N) return;
    int lane = threadIdx.x & 63;
    int n8 = lane >> 3;
    int dp = lane & 7;
    int start = row_ptr[wid];
    int cntp = (deg[wid] + 7) & ~7;
    float dr = dis[wid];
    const int* colp = cols + start;
    int vbase = n8 << 2;
    int dpo = dp << 2;
    float s0 = 0.f, s1 = 0.f, s2 = 0.f, s3 = 0.f;
    float s4 = 0.f, s5 = 0.f, s6 = 0.f, s7 = 0.f;
    for (int chunk = 0; chunk < cntp; chunk += 64) {
        int cv = colp[chunk + lane];
        int nq = min(64, cntp - chunk) >> 3;
        nq = __builtin_amdgcn_readfirstlane(nq);
        int coq[8];
        uint4 vq[8];
#pragma unroll
        for (int q = 0; q < 8; ++q) {
            if (q < nq)
                coq[q] = __builtin_amdgcn_ds_bpermute((q << 5) + vbase, cv);
        }
#pragma unroll
        for (int q = 0; q < 8; ++q) {
            if (q < nq)
                vq[q] = *(const uint4*)(xs + (((unsigned)coq[q]) << 5) + dpo);
        }
#pragma unroll
        for (int q = 0; q < 8; ++q) {
            if (q < nq) {
                acc_bf2(vq[q].x, s0, s1);
                acc_bf2(vq[q].y, s2, s3);
                acc_bf2(vq[q].z, s4, s5);
                acc_bf2(vq[q].w, s6, s7);
            }
        }
    }
#pragma unroll
    for (int m = 8; m < 64; m <<= 1) {
        s0 += __shfl_xor(s0, m); s1 += __shfl_xor(s1, m);
        s2 += __shfl_xor(s2, m); s3 += __shfl_xor(s3, m);
        s4 += __shfl_xor(s4, m); s5 += __shfl_xor(s5, m);
        s6 += __shfl_xor(s6, m); s7 += __shfl_xor(s7, m);
    }
    if (n8 == 0) {
        float x30 = dr * s0, x31 = dr * s1, x32 = dr * s2, x33 = dr * s3;
        float x34 = dr * s4, x35 = dr * s5, x36 = dr * s6, x37 = dr * s7;
        const float4* ep = (wid < U) ? (ue4 + (size_t)wid * 16)
                                     : (ie4 + (size_t)(wid - U) * 16);
        float4 e0 = ep[2 * dp];
        float4 e1 = ep[2 * dp + 1];
        uint4 h1 = ((const uint4*)xh1)[(wid << 3) + dp];
        uint4 h2 = ((const uint4*)xh2)[(wid << 3) + dp];
        float4 o0, o1;
        o0.x = 0.25f * (e0.x + f16lo(h1.x) + f16lo(h2.x) + x30);
        o0.y = 0.25f * (e0.y + f16hi(h1.x) + f16hi(h2.x) + x31);
        o0.z = 0.25f * (e0.z + f16lo(h1.y) + f16lo(h2.y) + x32);
        o0.w = 0.25f * (e0.w + f16hi(h1.y) + f16hi(h2.y) + x33);
        o1.x = 0.25f * (e1.x + f16lo(h1.z) + f16lo(h2.z) + x34);
        o1.y = 0.25f * (e1.y + f16hi(h1.z) + f16hi(h2.z) + x35);
        o1.z = 0.25f * (e1.z + f16lo(h1.w) + f16lo(h2.w) + x36);
        o1.w = 0.25f * (e1.w + f16hi(h1.w) + f16hi(h2.w) + x37);
        int oo = (wid << 4) + (dp << 1);
        out4[oo] = o0;
        out4[oo + 1] = o1;
    }
}

extern "C" void kernel_launch(void* const* d_in, const int* in_sizes, int n_in,
                              void* d_out, int out_size, void* d_ws, size_t ws_size,
                              hipStream_t stream) {
    const float* ue = (const float*)d_in[0];
    const float* ie = (const float*)d_in[1];
    const int* eu = (const int*)d_in[2];
    const int* ei = (const int*)d_in[3];
    const int U = in_sizes[0] / D; // 100001
    const int I = in_sizes[1] / D; // 50001
    const int N = U + I;           // 150002
    const int E = in_sizes[2];     // 4,000,000
    const int twoE = 2 * E;
    const int KB = (N + BROWS - 1) / BROWS; // 587
    float* out = (float*)d_out;

    char* ws = (char*)d_ws;
    auto alloc = [&](size_t bytes) {
        char* p = ws;
        ws += (bytes + 255) & ~(size_t)255;
        return p;
    };
    int* deg = (int*)alloc((size_t)N * 4);
    int* row_ptr = (int*)alloc((size_t)N * 4);
    float* dis = (float*)alloc((size_t)N * 4);
    int* bcnt = (int*)alloc(KP * 4);
    int* bbase = (int*)alloc((KP + 1) * 4);
    int* bcursor = (int*)alloc(KP * 4);
    int* cols = (int*)alloc(((size_t)twoE + (size_t)PADSLACK * (KB + 1) + COLS_SLACK) * 4);
    unsigned* pairs = (unsigned*)alloc((size_t)twoE * 4);       // 32 MB
    unsigned* xsA = (unsigned*)alloc(((size_t)N + 1) * 32 * 4); // bf16x2, +sentinel row
    unsigned* xsB = (unsigned*)alloc(((size_t)N + 1) * 32 * 4);
    // xh1 aliases `pairs` (dead after csr_build; 19.2MB <= 32MB). xh2 fresh.
    unsigned* xh1 = pairs;
    unsigned* xh2 = (unsigned*)alloc((size_t)N * 32 * 4);

    hipMemsetAsync(bcnt, 0, KP * 4, stream);
    bucket_count<<<1024, 256, 0, stream>>>(eu, ei, bcnt, E, U);
    bscan<<<1, KP, 0, stream>>>(bcnt, bbase, bcursor, KB, twoE);
    bucket_scatter<<<(twoE + TILE - 1) / TILE, 256, 0, stream>>>(
        eu, ei, bcursor, pairs, E, U, twoE);
    csr_build<<<KB, BROWS, 0, stream>>>(pairs, bbase, deg, row_ptr, dis, cols, N);

    int N8 = N * 8, U8 = U * 8;
    init_kernel<<<(N8 + 8 + 255) / 256, 256, 0, stream>>>(
        (const float4*)ue, (const float4*)ie, dis,
        (uint4*)xsA, (uint4*)xsB, U8, N8);

    int nblocks = (N + 3) / 4;
    // layer 0: xs0(A) -> xs1(B), xh1 = x1 (f16)
    spmm_mid<<<nblocks, 256, 0, stream>>>(
        row_ptr, deg, dis, cols, xsA, xsB, xh1, N);
    // layer 1: xs1(B) -> xs2(A; A is dead, sentinel intact), xh2 = x2 (f16)
    spmm_mid<<<nblocks, 256, 0, stream>>>(
        row_ptr, deg, dis, cols, xsB, xsA, xh2, N);
    // layer 2: gather xs2(A); out = 0.25*(emb + x1 + x2 + x3)
    spmm_last<<<nblocks, 256, 0, stream>>>(
        row_ptr, deg, dis, cols, xsA,
        (const float4*)ue, (const float4*)ie, xh1, xh2, (float4*)out, U, N);
}